// Round 18
// baseline (188.406 us; speedup 1.0000x reference)
//
#include <hip/hip_runtime.h>

// HyperMixer fused kernel, MI355X (gfx950) — round 18.
// x[8192,4,2048] f32, out[8192,2048] f32, W[24][8192] f32 -> y + collapsed.
//
// r10-r17 model: resident blocks run phases in LOCKSTEP -> chip alternates
// memory bursts (VALU idle) / compute bursts (HBM idle); additive ~90us
// mem + ~45us VALU + serial ~ 180us == measured. Allocator pins 52 VGPR
// (r13/r14/r17), vetoing register-level pipelining. This round:
//  - phase 0 = 8 global_load_lds issues (ZERO VGPRs -> allocator can't
//    re-serialize; 64 KB in flight) + barrier drain; f32 straight to LDS.
//  - NO f16 conversion pass, no xh: phase A reads f32 from LDS, inline
//    v_cvt_pkrtz -> dot2 against r6's PERMUTED f16 W (one uint4 W load
//    pairs with two conflict-free ds_read_b128 x reads). Sumsq folds
//    into wave 7's phase-A scan (exact f32).
//  - phase B reads f32 x (accuracy up: only W is f16 now).
// TOKS=2 (W shared across both tokens in the j-loop), LDS 66 KB ->
// 2 blocks/CU; one block's drain overlaps the peer's compute.
// Kept: scalar 2-lane sinkhorn (r13), bounded unroll (r9), bare
// __launch_bounds__ (r7/r8). Tripwire: WRITE_SIZE == 327,680 KB.

#define EPS 1e-6f
constexpr int D_ = 2048, KD = 8192, NOUT = 24;
constexpr int NTOK = 8192;
constexpr int TPB = 512;
constexpr int TOKS = 2;
constexpr int NBLK = NTOK / TOKS;   // 4096

typedef _Float16 h2 __attribute__((ext_vector_type(2)));

static __device__ __forceinline__ unsigned int pk2(float a, float b) {
#if __has_builtin(__builtin_amdgcn_cvt_pkrtz)
    auto r = __builtin_amdgcn_cvt_pkrtz(a, b);       // v_cvt_pkrtz_f16_f32
    return __builtin_bit_cast(unsigned int, r);
#else
    h2 h; h.x = (_Float16)a; h.y = (_Float16)b;
    return __builtin_bit_cast(unsigned int, h);
#endif
}

static __device__ __forceinline__ float dot2(unsigned int w, unsigned int x, float c) {
#if __has_builtin(__builtin_amdgcn_fdot2)
    return __builtin_amdgcn_fdot2(__builtin_bit_cast(h2, w),
                                  __builtin_bit_cast(h2, x), c, false);
#else
    h2 hw = __builtin_bit_cast(h2, w), hx = __builtin_bit_cast(h2, x);
    return c + (float)hw.x * (float)hx.x + (float)hw.y * (float)hx.y;
#endif
}

static __device__ __forceinline__ float frcp(float v) {
#if __has_builtin(__builtin_amdgcn_rcpf)
    return __builtin_amdgcn_rcpf(v);
#else
    return 1.f / v;
#endif
}

// Permuted f16 W (r6-proven layout): group g=(o*16+it)*64+lane holds
// e0..3 = W[o][it*512+lane*4+0..3], e4..7 = W[o][it*512+256+lane*4+0..3].
__global__ void conv_w_kernel(const float* __restrict__ W, uint4* __restrict__ Wh4) {
    int g = blockIdx.x * blockDim.x + threadIdx.x;   // 24576 threads
    int o = g >> 10, rem = g & 1023;
    int it = rem >> 6, lane = rem & 63;
    const float* src = W + o * KD + it * 512 + lane * 4;
    float4 a = *reinterpret_cast<const float4*>(src);
    float4 b = *reinterpret_cast<const float4*>(src + 256);
    uint4 u;
    u.x = pk2(a.x, a.y); u.y = pk2(a.z, a.w);
    u.z = pk2(b.x, b.y); u.w = pk2(b.z, b.w);
    Wh4[g] = u;
}

__global__ __launch_bounds__(TPB) void hypermix_kernel(
    const float* __restrict__ x, const float* __restrict__ outp,
    const uint4* __restrict__ Wh4,
    const float* __restrict__ scale, const float* __restrict__ base,
    float* __restrict__ y, float* __restrict__ coll)
{
    const int t = threadIdx.x;
    const int w = t >> 6, lane = t & 63;
    const size_t gt0 = (size_t)blockIdx.x * TOKS;

    __shared__ float stage[TOKS][KD];   // 64 KB f32 x (both tokens)
    __shared__ float ssv[TOKS];
    __shared__ float lg[TOKS][NOUT];
    __shared__ float wts[TOKS][NOUT];

    // ---- phase 0: direct HBM->LDS, zero-VGPR issues, one drain ----
#pragma unroll
    for (int tt = 0; tt < TOKS; ++tt) {
        const float* gsrc = x + (gt0 + tt) * KD + t * 4;
#pragma unroll
        for (int i = 0; i < 4; ++i)
            __builtin_amdgcn_global_load_lds(
                (const __attribute__((address_space(1))) unsigned int*)(gsrc + i * 2048),
                (__attribute__((address_space(3))) unsigned int*)(&stage[tt][i * 2048 + t * 4]),
                16, 0, 0);
    }
    __syncthreads();   // vmcnt drain: stage ready

    // ---- phase A: wave w -> rows 3w..3w+2, both tokens; inline cvt ----
    {
        const int r0 = w * 3;
        float acc[3][2];
#pragma unroll
        for (int j = 0; j < 3; ++j) { acc[j][0] = 0.f; acc[j][1] = 0.f; }
        float ss0 = 0.f, ss1 = 0.f;

#pragma unroll 2
        for (int it = 0; it < 16; ++it) {
            const int f = it * 512 + lane * 4;
            float4 x00 = *reinterpret_cast<const float4*>(&stage[0][f]);
            float4 x01 = *reinterpret_cast<const float4*>(&stage[0][f + 256]);
            float4 x10 = *reinterpret_cast<const float4*>(&stage[1][f]);
            float4 x11 = *reinterpret_cast<const float4*>(&stage[1][f + 256]);
            if (w == 7) {   // wave-uniform branch: exact-f32 sumsq
                ss0 += x00.x * x00.x + x00.y * x00.y + x00.z * x00.z + x00.w * x00.w
                     + x01.x * x01.x + x01.y * x01.y + x01.z * x01.z + x01.w * x01.w;
                ss1 += x10.x * x10.x + x10.y * x10.y + x10.z * x10.z + x10.w * x10.w
                     + x11.x * x11.x + x11.y * x11.y + x11.z * x11.z + x11.w * x11.w;
            }
            unsigned int p00 = pk2(x00.x, x00.y), p01 = pk2(x00.z, x00.w);
            unsigned int p02 = pk2(x01.x, x01.y), p03 = pk2(x01.z, x01.w);
            unsigned int p10 = pk2(x10.x, x10.y), p11 = pk2(x10.z, x10.w);
            unsigned int p12 = pk2(x11.x, x11.y), p13 = pk2(x11.z, x11.w);
#pragma unroll
            for (int j = 0; j < 3; ++j) {
                uint4 wv = Wh4[(size_t)(r0 + j) * 1024 + it * 64 + lane];
                acc[j][0] = dot2(wv.x, p00, acc[j][0]);
                acc[j][0] = dot2(wv.y, p01, acc[j][0]);
                acc[j][0] = dot2(wv.z, p02, acc[j][0]);
                acc[j][0] = dot2(wv.w, p03, acc[j][0]);
                acc[j][1] = dot2(wv.x, p10, acc[j][1]);
                acc[j][1] = dot2(wv.y, p11, acc[j][1]);
                acc[j][1] = dot2(wv.z, p12, acc[j][1]);
                acc[j][1] = dot2(wv.w, p13, acc[j][1]);
            }
        }
#pragma unroll
        for (int j = 0; j < 3; ++j) {
            float v0 = acc[j][0], v1 = acc[j][1];
#pragma unroll
            for (int m = 1; m < 64; m <<= 1) {
                v0 += __shfl_xor(v0, m, 64);
                v1 += __shfl_xor(v1, m, 64);
            }
            if (lane == 0) { lg[0][r0 + j] = v0; lg[1][r0 + j] = v1; }
        }
        if (w == 7) {
#pragma unroll
            for (int m = 1; m < 64; m <<= 1) {
                ss0 += __shfl_xor(ss0, m, 64);
                ss1 += __shfl_xor(ss1, m, 64);
            }
            if (lane == 0) { ssv[0] = ss0; ssv[1] = ss1; }
        }
    }
    __syncthreads();

    // ---- weights: 2 threads, scalar sinkhorn in regs (r13-proven) ----
    if (t < TOKS) {
        float rms = rsqrtf(ssv[t] * (1.f / 8192.f) + EPS);
        float s0 = scale[0], s1 = scale[1], s2 = scale[2];
        float l[24];
#pragma unroll
        for (int i = 0; i < 24; ++i) l[i] = lg[t][i];
#pragma unroll
        for (int k = 0; k < 4; ++k) {
            float z0 = l[k] * rms * s0 + base[k];
            wts[t][k] = frcp(1.f + __expf(-z0)) + EPS;
            float z1 = l[4 + k] * rms * s1 + base[4 + k];
            wts[t][4 + k] = 2.f * frcp(1.f + __expf(-z1));
        }
        float p[16];
#pragma unroll
        for (int h = 0; h < 4; ++h) {
            float c0 = l[8 + h * 4 + 0] * rms * s2 + base[8 + h * 4 + 0];
            float c1 = l[8 + h * 4 + 1] * rms * s2 + base[8 + h * 4 + 1];
            float c2 = l[8 + h * 4 + 2] * rms * s2 + base[8 + h * 4 + 2];
            float c3 = l[8 + h * 4 + 3] * rms * s2 + base[8 + h * 4 + 3];
            float mx = fmaxf(fmaxf(c0, c1), fmaxf(c2, c3));
            float e0 = __expf(c0 - mx), e1 = __expf(c1 - mx);
            float e2 = __expf(c2 - mx), e3 = __expf(c3 - mx);
            float inv = frcp(e0 + e1 + e2 + e3);
            p[0 + h * 4] = e0 * inv + EPS; p[1 + h * 4] = e1 * inv + EPS;
            p[2 + h * 4] = e2 * inv + EPS; p[3 + h * 4] = e3 * inv + EPS;
        }
#pragma unroll
        for (int k = 0; k < 4; ++k) {
            float inv = frcp(p[k] + p[4 + k] + p[8 + k] + p[12 + k] + EPS);
            p[k] *= inv; p[4 + k] *= inv; p[8 + k] *= inv; p[12 + k] *= inv;
        }
#pragma unroll 1
        for (int itn = 0; itn < 19; ++itn) {
#pragma unroll
            for (int h = 0; h < 4; ++h) {
                float inv = frcp(p[h * 4] + p[h * 4 + 1] + p[h * 4 + 2] + p[h * 4 + 3] + EPS);
                p[h * 4] *= inv; p[h * 4 + 1] *= inv; p[h * 4 + 2] *= inv; p[h * 4 + 3] *= inv;
            }
#pragma unroll
            for (int k = 0; k < 4; ++k) {
                float inv = frcp(p[k] + p[4 + k] + p[8 + k] + p[12 + k] + EPS);
                p[k] *= inv; p[4 + k] *= inv; p[8 + k] *= inv; p[12 + k] *= inv;
            }
        }
#pragma unroll
        for (int i = 0; i < 16; ++i) wts[t][8 + i] = p[i];
    }
    __syncthreads();

    // ---- phase B: f32 x from LDS; out loaded up front; pure writes ----
    {
        float4 ov0 = *reinterpret_cast<const float4*>(outp + gt0 * D_ + t * 4);
        float4 ov1 = *reinterpret_cast<const float4*>(outp + (gt0 + 1) * D_ + t * 4);
#pragma unroll
        for (int tt = 0; tt < TOKS; ++tt) {
            float pre[4], post[4], cmb[4][4];
#pragma unroll
            for (int k = 0; k < 4; ++k) { pre[k] = wts[tt][k]; post[k] = wts[tt][4 + k]; }
#pragma unroll
            for (int h = 0; h < 4; ++h)
#pragma unroll
                for (int k = 0; k < 4; ++k) cmb[h][k] = wts[tt][8 + h * 4 + k];

            const int d = t * 4;
            float4 xk[4];
#pragma unroll
            for (int k = 0; k < 4; ++k)
                xk[k] = *reinterpret_cast<const float4*>(&stage[tt][k * D_ + d]);
            const float xe[4][4] = {
                {xk[0].x, xk[0].y, xk[0].z, xk[0].w},
                {xk[1].x, xk[1].y, xk[1].z, xk[1].w},
                {xk[2].x, xk[2].y, xk[2].z, xk[2].w},
                {xk[3].x, xk[3].y, xk[3].z, xk[3].w}};
            float4 ov = tt ? ov1 : ov0;
            const float oe[4] = {ov.x, ov.y, ov.z, ov.w};

            float* yb = y + (gt0 + tt) * KD;
            float* cb = coll + (gt0 + tt) * D_;
            float cv[4], yv[4];
#pragma unroll
            for (int e = 0; e < 4; ++e)
                cv[e] = pre[0] * xe[0][e] + pre[1] * xe[1][e]
                      + pre[2] * xe[2][e] + pre[3] * xe[3][e];
            *reinterpret_cast<float4*>(cb + d) = make_float4(cv[0], cv[1], cv[2], cv[3]);
#pragma unroll
            for (int h = 0; h < 4; ++h) {
#pragma unroll
                for (int e = 0; e < 4; ++e)
                    yv[e] = post[h] * oe[e] + cmb[h][0] * xe[0][e] + cmb[h][1] * xe[1][e]
                          + cmb[h][2] * xe[2][e] + cmb[h][3] * xe[3][e];
                *reinterpret_cast<float4*>(yb + h * D_ + d) =
                    make_float4(yv[0], yv[1], yv[2], yv[3]);
            }
        }
    }
}

extern "C" void kernel_launch(void* const* d_in, const int* in_sizes, int n_in,
                              void* d_out, int out_size, void* d_ws, size_t ws_size,
                              hipStream_t stream) {
    const float* x     = (const float*)d_in[0];
    const float* outp  = (const float*)d_in[1];
    const float* W     = (const float*)d_in[2];
    const float* scale = (const float*)d_in[3];
    const float* base  = (const float*)d_in[4];
    float* y    = (float*)d_out;
    float* coll = y + (size_t)NTOK * KD;   // 67108864

    uint4* Wh4 = (uint4*)d_ws;     // 384 KB f16 permuted (ws is larger)
    conv_w_kernel<<<NOUT * KD / 8 / 256, 256, 0, stream>>>(W, Wh4);
    hypermix_kernel<<<NBLK, TPB, 0, stream>>>(x, outp, Wh4, scale, base, y, coll);
}